// Round 11
// baseline (371.459 us; speedup 1.0000x reference)
//
#include <hip/hip_runtime.h>
#include <cmath>

typedef __bf16 bf16;
typedef __attribute__((ext_vector_type(4))) __bf16 bf16x4;
typedef __attribute__((ext_vector_type(8))) __bf16 bf16x8;
typedef __attribute__((ext_vector_type(4))) float f32x4;

#define MFMA16(a, b, c) __builtin_amdgcn_mfma_f32_16x16x32_bf16((a), (b), (c), 0, 0, 0)
#define SETPRIO1 __builtin_amdgcn_s_setprio(1)
#define SETPRIO0 __builtin_amdgcn_s_setprio(0)
#define EXP2(x) __builtin_amdgcn_exp2f(x)
// fused waitcnt+barrier in ONE asm so no memory op can slip between them
#define WAITV_BAR(N) asm volatile("s_waitcnt vmcnt(" #N ")\n\ts_barrier" ::: "memory")
#define WAITL_BAR    asm volatile("s_waitcnt lgkmcnt(0)\n\ts_barrier" ::: "memory")

#define LOG2E 1.4426950408889634f

static __device__ __forceinline__ void gload16(const bf16* g, bf16* l)
{
  __builtin_amdgcn_global_load_lds((const __attribute__((address_space(1))) void*)g,
                                   (__attribute__((address_space(3))) void*)l, 16, 0, 0);
}

static __device__ __forceinline__ void split4(const float4 v, bf16x4& h, bf16x4& l)
{
  h[0] = (bf16)v.x; l[0] = (bf16)(v.x - (float)h[0]);
  h[1] = (bf16)v.y; l[1] = (bf16)(v.y - (float)h[1]);
  h[2] = (bf16)v.z; l[2] = (bf16)(v.z - (float)h[2]);
  h[3] = (bf16)v.w; l[3] = (bf16)(v.w - (float)h[3]);
}

// ---- conv: one-time fp32 -> bf16 (hi/lo or single) conversion of inputs/weights ----
__global__ __launch_bounds__(256) void conv_kernel(
    const float* __restrict__ query, const float* __restrict__ key, const float* __restrict__ value,
    const float* __restrict__ Wq, const float* __restrict__ Wk, const float* __restrict__ Wv,
    const float* __restrict__ Wo,
    bf16* __restrict__ qh, bf16* __restrict__ ql, bf16* __restrict__ kh, bf16* __restrict__ kl,
    bf16* __restrict__ wqh, bf16* __restrict__ wql, bf16* __restrict__ wkh, bf16* __restrict__ wkl,
    bf16* __restrict__ vb, bf16* __restrict__ wvb, bf16* __restrict__ wob)
{
  const int i = blockIdx.x * 256 + threadIdx.x;   // float4 index, 4,194,304 total
  const float* src;
  bf16 *dh, *dl;
  int e;
  if (i < 1048576)      { src = query; dh = qh; dl = ql; e = i; }
  else if (i < 2097152) { src = key;   dh = kh; dl = kl; e = i - 1048576; }
  else if (i < 3145728) { src = value; dh = vb; dl = nullptr; e = i - 2097152; }
  else {
    const int w = i - 3145728;
    const int which = w >> 18;
    e = w & 262143;
    src = (which == 0) ? Wq : (which == 1) ? Wk : (which == 2) ? Wv : Wo;
    dh  = (which == 0) ? wqh : (which == 1) ? wkh : (which == 2) ? wvb : wob;
    dl  = (which == 0) ? wql : (which == 1) ? wkl : nullptr;
  }
  const float4 v = ((const float4*)src)[e];
  bf16x4 h, l;
  split4(v, h, l);
  *(bf16x4*)(dh + (size_t)e * 4) = h;
  if (dl) *(bf16x4*)(dl + (size_t)e * 4) = l;
}

// ---- projqk: split-bf16 3-pass MFMA GEMM, gload_lds dbuf pipeline, RoPE fused epilogue ----
// K output pre-scaled by 8*log2e so downstream softmax uses bare v_exp_f32 (2^x)
__global__ __launch_bounds__(256) void projqk_kernel(
    const bf16* __restrict__ qh, const bf16* __restrict__ ql,
    const bf16* __restrict__ kh, const bf16* __restrict__ kl,
    const bf16* __restrict__ wqh, const bf16* __restrict__ wql,
    const bf16* __restrict__ wkh, const bf16* __restrict__ wkl,
    bf16* __restrict__ Qh_g, bf16* __restrict__ Ql_g,
    bf16* __restrict__ Kh_g, bf16* __restrict__ Kl_g)
{
  const int which = blockIdx.y;
  const bf16* ta[4];
  ta[0] = which ? kh : qh;   ta[1] = which ? kl : ql;
  ta[2] = which ? wkh : wqh; ta[3] = which ? wkl : wql;
  bf16* oh = which ? Kh_g : Qh_g;
  bf16* ol = which ? Kl_g : Ql_g;
  const float oscale = which ? 8.0f * LOG2E : 1.0f;

  __shared__ __align__(16) bf16 sm[2][4][4096];   // [buf][Ah,Al,Bh,Bl][128*32]
  const int tid = threadIdx.x, lane = tid & 63, w = tid >> 6;
  const int wm = w >> 1, wn = w & 1;
  const int fr = lane & 15, fg = lane >> 4;
  const int bm = blockIdx.x >> 3, bn = blockIdx.x & 7;
  const int rb[4] = {bm * 128, bm * 128, bn * 128, bn * 128};
  const int lrow = lane >> 2, lcol = (lane & 3) * 8;

  auto stage = [&](int buf, int kt) {
#pragma unroll
    for (int tl = 0; tl < 4; ++tl)
#pragma unroll
      for (int q = 0; q < 2; ++q) {
        const int r = (q * 4 + w) * 16 + lrow;
        gload16(ta[tl] + (size_t)(rb[tl] + r) * 1024 + kt * 32 + lcol,
                &sm[buf][tl][(q * 4 + w) * 512]);
      }
  };

  f32x4 acc[4][4] = {};
  stage(0, 0);
  for (int kt = 0; kt < 32; ++kt) {
    const int cur = kt & 1;
    if (kt < 31) { stage(cur ^ 1, kt + 1); WAITV_BAR(8); }
    else         { WAITV_BAR(0); }
    bf16x8 afh[4], afl[4], bfh[4], bfl[4];
#pragma unroll
    for (int m = 0; m < 4; ++m) {
      afh[m] = *(bf16x8*)&sm[cur][0][(wm * 64 + m * 16 + fr) * 32 + fg * 8];
      afl[m] = *(bf16x8*)&sm[cur][1][(wm * 64 + m * 16 + fr) * 32 + fg * 8];
    }
#pragma unroll
    for (int n = 0; n < 4; ++n) {
      bfh[n] = *(bf16x8*)&sm[cur][2][(wn * 64 + n * 16 + fr) * 32 + fg * 8];
      bfl[n] = *(bf16x8*)&sm[cur][3][(wn * 64 + n * 16 + fr) * 32 + fg * 8];
    }
    SETPRIO1;
#pragma unroll
    for (int m = 0; m < 4; ++m)
#pragma unroll
      for (int n = 0; n < 4; ++n) {
        acc[m][n] = MFMA16(afh[m], bfh[n], acc[m][n]);
        acc[m][n] = MFMA16(afh[m], bfl[n], acc[m][n]);
        acc[m][n] = MFMA16(afl[m], bfh[n], acc[m][n]);
      }
    SETPRIO0;
    WAITL_BAR;
  }
  // epilogue: RoPE (first 32 dims of each head, interleaved pairs), scale, split, store
#pragma unroll
  for (int n = 0; n < 4; ++n) {
    const int d = n * 16 + fr;
    const bool rot = (n < 2);
    const float invf = rot ? exp2f((float)(d >> 1) * (-0.83048202372184059f)) : 0.0f;
    const int odd = d & 1;
    const int col = bn * 128 + wn * 64 + n * 16 + fr;
#pragma unroll
    for (int m = 0; m < 4; ++m)
#pragma unroll
      for (int r4 = 0; r4 < 4; ++r4) {
        const int row = bm * 128 + wm * 64 + m * 16 + fg * 4 + r4;
        float x = acc[m][n][r4];
        const float p = __shfl_xor(x, 1);
        if (rot) {
          float sn, cs;
          sincosf((float)(row & 2047) * invf, &sn, &cs);
          x = odd ? x * cs + p * sn : x * cs - p * sn;
        }
        x *= oscale;
        const bf16 hv = (bf16)x;
        oh[(size_t)row * 1024 + col] = hv;
        ol[(size_t)row * 1024 + col] = (bf16)(x - (float)hv);
      }
  }
}

// ---- projv: 1-pass bf16 GEMM, gload_lds dbuf; writes V^T per-head bf16 ----
__global__ __launch_bounds__(256) void projv_kernel(const bf16* __restrict__ vb,
                                                    const bf16* __restrict__ wvb,
                                                    bf16* __restrict__ Vt_g)
{
  __shared__ __align__(16) bf16 sm[2][2][4096];
  const int tid = threadIdx.x, lane = tid & 63, w = tid >> 6;
  const int wm = w >> 1, wn = w & 1;
  const int fr = lane & 15, fg = lane >> 4;
  const int bm = blockIdx.x >> 3, bn = blockIdx.x & 7;
  const int lrow = lane >> 2, lcol = (lane & 3) * 8;

  auto stage = [&](int buf, int kt) {
#pragma unroll
    for (int q = 0; q < 2; ++q) {
      const int r = (q * 4 + w) * 16 + lrow;
      gload16(vb  + (size_t)(bm * 128 + r) * 1024 + kt * 32 + lcol, &sm[buf][0][(q * 4 + w) * 512]);
      gload16(wvb + (size_t)(bn * 128 + r) * 1024 + kt * 32 + lcol, &sm[buf][1][(q * 4 + w) * 512]);
    }
  };

  f32x4 acc[4][4] = {};
  stage(0, 0);
  for (int kt = 0; kt < 32; ++kt) {
    const int cur = kt & 1;
    if (kt < 31) { stage(cur ^ 1, kt + 1); WAITV_BAR(4); }
    else         { WAITV_BAR(0); }
    bf16x8 af[4], bf[4];
#pragma unroll
    for (int m = 0; m < 4; ++m) af[m] = *(bf16x8*)&sm[cur][0][(wm * 64 + m * 16 + fr) * 32 + fg * 8];
#pragma unroll
    for (int n = 0; n < 4; ++n) bf[n] = *(bf16x8*)&sm[cur][1][(wn * 64 + n * 16 + fr) * 32 + fg * 8];
    SETPRIO1;
#pragma unroll
    for (int m = 0; m < 4; ++m)
#pragma unroll
      for (int n = 0; n < 4; ++n) acc[m][n] = MFMA16(af[m], bf[n], acc[m][n]);
    SETPRIO0;
    WAITL_BAR;
  }
#pragma unroll
  for (int m = 0; m < 4; ++m) {
    const int row0 = bm * 128 + wm * 64 + m * 16 + fg * 4;
    const int b = row0 >> 11, l0 = row0 & 2047;
#pragma unroll
    for (int n = 0; n < 4; ++n) {
      const int col = bn * 128 + wn * 64 + n * 16 + fr;
      const int h = col >> 6, d = col & 63;
      bf16x4 pk;
#pragma unroll
      for (int j = 0; j < 4; ++j) pk[j] = (bf16)acc[m][n][j];
      *(bf16x4*)(Vt_g + ((size_t)((b * 16 + h) * 64 + d)) * 2048 + l0) = pk;
    }
  }
}

// ---- out: 1-pass bf16 GEMM, gload_lds dbuf; + bias -> fp32 ----
__global__ __launch_bounds__(256) void out_kernel(const bf16* __restrict__ attnb,
                                                  const bf16* __restrict__ wob,
                                                  const float* __restrict__ bo,
                                                  float* __restrict__ out)
{
  __shared__ __align__(16) bf16 sm[2][2][4096];
  const int tid = threadIdx.x, lane = tid & 63, w = tid >> 6;
  const int wm = w >> 1, wn = w & 1;
  const int fr = lane & 15, fg = lane >> 4;
  const int bm = blockIdx.x >> 3, bn = blockIdx.x & 7;
  const int lrow = lane >> 2, lcol = (lane & 3) * 8;

  auto stage = [&](int buf, int kt) {
#pragma unroll
    for (int q = 0; q < 2; ++q) {
      const int r = (q * 4 + w) * 16 + lrow;
      gload16(attnb + (size_t)(bm * 128 + r) * 1024 + kt * 32 + lcol, &sm[buf][0][(q * 4 + w) * 512]);
      gload16(wob   + (size_t)(bn * 128 + r) * 1024 + kt * 32 + lcol, &sm[buf][1][(q * 4 + w) * 512]);
    }
  };

  f32x4 acc[4][4] = {};
  stage(0, 0);
  for (int kt = 0; kt < 32; ++kt) {
    const int cur = kt & 1;
    if (kt < 31) { stage(cur ^ 1, kt + 1); WAITV_BAR(4); }
    else         { WAITV_BAR(0); }
    bf16x8 af[4], bf[4];
#pragma unroll
    for (int m = 0; m < 4; ++m) af[m] = *(bf16x8*)&sm[cur][0][(wm * 64 + m * 16 + fr) * 32 + fg * 8];
#pragma unroll
    for (int n = 0; n < 4; ++n) bf[n] = *(bf16x8*)&sm[cur][1][(wn * 64 + n * 16 + fr) * 32 + fg * 8];
    SETPRIO1;
#pragma unroll
    for (int m = 0; m < 4; ++m)
#pragma unroll
      for (int n = 0; n < 4; ++n) acc[m][n] = MFMA16(af[m], bf[n], acc[m][n]);
    SETPRIO0;
    WAITL_BAR;
  }
#pragma unroll
  for (int m = 0; m < 4; ++m)
#pragma unroll
    for (int n = 0; n < 4; ++n) {
      const int col = bn * 128 + wn * 64 + n * 16 + fr;
      const float bv = bo[col];
#pragma unroll
      for (int r4 = 0; r4 < 4; ++r4) {
        const int row = bm * 128 + wm * 64 + m * 16 + fg * 4 + r4;
        out[(size_t)row * 1024 + col] = acc[m][n][r4] + bv;
      }
    }
}

// ---- stats: per-(b,h,j) column max (log2 domain) + reciprocal sum of exp2 ----
// per-lane online (max,sum) over the lane's i-subset; ONE cross-lane combine at end
__global__ __launch_bounds__(512) void stats_kernel(const bf16* __restrict__ Qh_g, const bf16* __restrict__ Ql_g,
                                                    const bf16* __restrict__ Kh_g, const bf16* __restrict__ Kl_g,
                                                    float* __restrict__ colmax, float* __restrict__ csuminv)
{
  __shared__ __align__(16) bf16 smh[2][8192], sml[2][8192];   // [buf][128*64], K staged via buf1
  const int swz = (blockIdx.x & 7) * 64 + (blockIdx.x >> 3);
  const int bh = swz >> 4, jb = swz & 15;
  const int b = bh >> 4, h = bh & 15;
  const int t = threadIdx.x, lane = t & 63, w = t >> 6;
  const int fr = lane & 15, fg = lane >> 4;
  const int lr = lane >> 3, lc = lane & 7;

  auto stageQ = [&](int buf, int it) {
#pragma unroll
    for (int q = 0; q < 2; ++q) {
      const int r = (q * 8 + w) * 8 + lr;
      const size_t g = (size_t)(b * 2048 + it * 128 + r) * 1024 + h * 64 + ((lc ^ (r & 7)) * 8);
      gload16(Qh_g + g, &smh[buf][(q * 8 + w) * 512]);
      gload16(Ql_g + g, &sml[buf][(q * 8 + w) * 512]);
    }
  };

  // stage K into buf1 (4 ops), then Q it=0 into buf0 (4 ops)
#pragma unroll
  for (int q = 0; q < 2; ++q) {
    const int r = (q * 8 + w) * 8 + lr;
    const size_t g = (size_t)(b * 2048 + jb * 128 + r) * 1024 + h * 64 + ((lc ^ (r & 7)) * 8);
    gload16(Kh_g + g, &smh[1][(q * 8 + w) * 512]);
    gload16(Kl_g + g, &sml[1][(q * 8 + w) * 512]);
  }
  stageQ(0, 0);
  WAITV_BAR(4);              // K done (Q0 still in flight)
  bf16x8 kfh[2], kfl[2];
#pragma unroll
  for (int ks = 0; ks < 2; ++ks) {
    const int rr = w * 16 + fr;
    const int cc = (ks * 32 + fg * 8) ^ ((rr & 7) << 3);
    kfh[ks] = *(bf16x8*)&smh[1][rr * 64 + cc];
    kfl[ks] = *(bf16x8*)&sml[1][rr * 64 + cc];
  }
  WAITL_BAR;                 // K frag reads done -> buf1 reusable

  float rm[4] = {-1e30f, -1e30f, -1e30f, -1e30f};
  float rs[4] = {0.f, 0.f, 0.f, 0.f};
  for (int it = 0; it < 16; ++it) {
    const int cur = it & 1;
    if (it < 15) { stageQ(cur ^ 1, it + 1); WAITV_BAR(4); }
    else         { WAITV_BAR(0); }
    f32x4 acc[8] = {};
    SETPRIO1;
#pragma unroll
    for (int ks = 0; ks < 2; ++ks)
#pragma unroll
      for (int n = 0; n < 8; ++n) {
        const int rr = n * 16 + fr;
        const int cc = (ks * 32 + fg * 8) ^ ((rr & 7) << 3);
        const bf16x8 qf = *(bf16x8*)&smh[cur][rr * 64 + cc];
        const bf16x8 lf = *(bf16x8*)&sml[cur][rr * 64 + cc];
        acc[n] = MFMA16(kfh[ks], qf, acc[n]);
        acc[n] = MFMA16(kfh[ks], lf, acc[n]);
        acc[n] = MFMA16(kfl[ks], qf, acc[n]);
      }
    SETPRIO0;
    // per-lane online update (no cross-lane ops in the loop)
#pragma unroll
    for (int r4 = 0; r4 < 4; ++r4) {
      const float m = fmaxf(fmaxf(fmaxf(acc[0][r4], acc[1][r4]), fmaxf(acc[2][r4], acc[3][r4])),
                            fmaxf(fmaxf(acc[4][r4], acc[5][r4]), fmaxf(acc[6][r4], acc[7][r4])));
      const float mn = fmaxf(rm[r4], m);
      float ts = 0.f;
#pragma unroll
      for (int n = 0; n < 8; ++n) ts += EXP2(acc[n][r4] - mn);
      rs[r4] = rs[r4] * EXP2(rm[r4] - mn) + ts;
      rm[r4] = mn;
    }
    WAITL_BAR;
  }
  // cross-lane combine: the 16 lanes varying fr share the same j (j = jb*128+w*16+fg*4+r4)
#pragma unroll
  for (int r4 = 0; r4 < 4; ++r4) {
    float M = rm[r4];
#pragma unroll
    for (int off = 1; off < 16; off <<= 1) M = fmaxf(M, __shfl_xor(M, off));
    float s = rs[r4] * EXP2(rm[r4] - M);
#pragma unroll
    for (int off = 1; off < 16; off <<= 1) s += __shfl_xor(s, off);
    rm[r4] = M;
    rs[r4] = s;
  }
  if (fr == 0) {
#pragma unroll
    for (int r4 = 0; r4 < 4; ++r4) {
      const int j = jb * 128 + w * 16 + fg * 4 + r4;
      colmax[bh * 2048 + j] = rm[r4];
      csuminv[bh * 2048 + j] = 1.0f / rs[r4];
    }
  }
}

// ---- attn: r10 structure; P global stores moved AFTER BAR1 (overlap with PV MFMA) ----
__global__ __launch_bounds__(256) void attn_kernel(const bf16* __restrict__ Qh_g, const bf16* __restrict__ Ql_g,
                                                   const bf16* __restrict__ Kh_g, const bf16* __restrict__ Kl_g,
                                                   const bf16* __restrict__ Vt_g,
                                                   const float* __restrict__ colmax, const float* __restrict__ csuminv,
                                                   float* __restrict__ P, bf16* __restrict__ attnb)
{
  __shared__ __align__(16) unsigned char smem[46080];
  bf16(*Kh)[72] = (bf16(*)[72])smem;                  // 64 rows
  bf16(*Kl)[72] = (bf16(*)[72])(smem + 9216);         // 64 rows
  bf16(*Vt)[72] = (bf16(*)[72])(smem + 18432);        // 64 rows: V^T [d][j]
  bf16(*Pb)[72] = (bf16(*)[72])(smem + 27648);        // 128 rows
  bf16(*Qh)[72] = (bf16(*)[72])smem;                  // overlay: 128 rows
  bf16(*Ql)[72] = (bf16(*)[72])(smem + 18432);        // overlay: 128 rows

  const int swz = (blockIdx.x & 7) * 64 + (blockIdx.x >> 3);
  const int bh = swz >> 4, ib = swz & 15;
  const int b = bh >> 4, h = bh & 15;
  const int t = threadIdx.x, lane = t & 63, w = t >> 6;
  const int fr = lane & 15, fg = lane >> 4;

  // stage Q i-block and preload fragments (once)
#pragma unroll
  for (int q = 0; q < 4; ++q) {
    const int u = q * 256 + t, r = u >> 3, c8 = (u & 7) * 8;
    const size_t g = (size_t)(b * 2048 + ib * 128 + r) * 1024 + h * 64 + c8;
    *(bf16x8*)&Qh[r][c8] = *(const bf16x8*)(Qh_g + g);
    *(bf16x8*)&Ql[r][c8] = *(const bf16x8*)(Ql_g + g);
  }
  WAITL_BAR;
  bf16x8 qfh[2][2], qfl[2][2];
#pragma unroll
  for (int mf = 0; mf < 2; ++mf)
#pragma unroll
    for (int ks = 0; ks < 2; ++ks) {
      qfh[mf][ks] = *(bf16x8*)&Qh[w * 32 + mf * 16 + fr][ks * 32 + fg * 8];
      qfl[mf][ks] = *(bf16x8*)&Ql[w * 32 + mf * 16 + fr][ks * 32 + fg * 8];
    }

  bf16x8 rKh[2], rKl[2], rV[2];
  auto loadT = [&](int jt1) {
#pragma unroll
    for (int q = 0; q < 2; ++q) {
      const int u = q * 256 + t, r = u >> 3, c8 = (u & 7) * 8;
      const size_t g = (size_t)(b * 2048 + jt1 * 64 + r) * 1024 + h * 64 + c8;
      rKh[q] = *(const bf16x8*)(Kh_g + g);
      rKl[q] = *(const bf16x8*)(Kl_g + g);
      rV[q]  = *(const bf16x8*)(Vt_g + (size_t)(bh * 64 + r) * 2048 + jt1 * 64 + c8);
    }
  };
  auto writeK = [&]() {
#pragma unroll
    for (int q = 0; q < 2; ++q) {
      const int u = q * 256 + t, r = u >> 3, c8 = (u & 7) * 8;
      *(bf16x8*)&Kh[r][c8] = rKh[q];
      *(bf16x8*)&Kl[r][c8] = rKl[q];
    }
  };
  auto writeV = [&]() {
#pragma unroll
    for (int q = 0; q < 2; ++q) {
      const int u = q * 256 + t, r = u >> 3, c8 = (u & 7) * 8;
      *(bf16x8*)&Vt[r][c8] = rV[q];
    }
  };

  loadT(0);
  WAITL_BAR;       // q-frag reads done -> K/V area free
  writeK(); writeV();
  WAITL_BAR;       // tile 0 visible

  f32x4 oacc[2][4] = {};
  for (int jt = 0; jt < 32; ++jt) {
    if (jt < 31) loadT(jt + 1);            // prefetch next tile into regs (hides under S+PV)
    // hoist stats loads: latency hides under S-MFMA
    float cmr[4], rcr[4];
#pragma unroll
    for (int nj = 0; nj < 4; ++nj) {
      const int jg = jt * 64 + nj * 16 + fr;
      cmr[nj] = colmax[bh * 2048 + jg];
      rcr[nj] = csuminv[bh * 2048 + jg];
    }
    // S tile = Q . K^T (scaled by 8*log2e via K)
    f32x4 s[2][4] = {};
    SETPRIO1;
#pragma unroll
    for (int ks = 0; ks < 2; ++ks)
#pragma unroll
      for (int nj = 0; nj < 4; ++nj) {
        const bf16x8 khf = *(bf16x8*)&Kh[nj * 16 + fr][ks * 32 + fg * 8];
        const bf16x8 klf = *(bf16x8*)&Kl[nj * 16 + fr][ks * 32 + fg * 8];
#pragma unroll
        for (int mf = 0; mf < 2; ++mf) {
          s[mf][nj] = MFMA16(qfh[mf][ks], khf, s[mf][nj]);
          s[mf][nj] = MFMA16(qfh[mf][ks], klf, s[mf][nj]);
          s[mf][nj] = MFMA16(qfl[mf][ks], khf, s[mf][nj]);
        }
      }
    SETPRIO0;
    // normalize in place (s := P) and stash bf16 copy in LDS; NO global stores yet
#pragma unroll
    for (int nj = 0; nj < 4; ++nj)
#pragma unroll
      for (int mf = 0; mf < 2; ++mf)
#pragma unroll
        for (int r4 = 0; r4 < 4; ++r4) {
          const int il = w * 32 + mf * 16 + fg * 4 + r4;
          const float pv = EXP2(s[mf][nj][r4] - cmr[nj]) * rcr[nj];
          s[mf][nj][r4] = pv;
          Pb[il][nj * 16 + fr] = (bf16)pv;
        }
    WAITL_BAR;     // BAR1: Pb visible; all waves past S-phase K reads
    if (jt < 31) writeK();                 // K not read by PV -> overlap
    // P global stores: issue here so they overlap PV MFMAs (no barrier dependency)
#pragma unroll
    for (int nj = 0; nj < 4; ++nj) {
      const int jg = jt * 64 + nj * 16 + fr;
#pragma unroll
      for (int mf = 0; mf < 2; ++mf)
#pragma unroll
        for (int r4 = 0; r4 < 4; ++r4) {
          const int il = w * 32 + mf * 16 + fg * 4 + r4;
          P[(size_t)(bh * 2048 + ib * 128 + il) * 2048 + jg] = s[mf][nj][r4];
        }
    }
    SETPRIO1;
#pragma unroll
    for (int ks = 0; ks < 2; ++ks) {
      bf16x8 pa[2];
#pragma unroll
      for (int mf = 0; mf < 2; ++mf) pa[mf] = *(bf16x8*)&Pb[w * 32 + mf * 16 + fr][ks * 32 + fg * 8];
#pragma unroll
      for (int nd = 0; nd < 4; ++nd) {
        const bf16x8 vbf = *(bf16x8*)&Vt[nd * 16 + fr][ks * 32 + fg * 8];
#pragma unroll
        for (int mf = 0; mf < 2; ++mf) oacc[mf][nd] = MFMA16(pa[mf], vbf, oacc[mf][nd]);
      }
    }
    SETPRIO0;
    WAITL_BAR;     // BAR2: PV done; writeK visible for next S
    if (jt < 31) writeV();                 // visible at next iter's BAR1
  }
#pragma unroll
  for (int mf = 0; mf < 2; ++mf)
#pragma unroll
    for (int nd = 0; nd < 4; ++nd)
#pragma unroll
      for (int r4 = 0; r4 < 4; ++r4) {
        const int il = ib * 128 + w * 32 + mf * 16 + fg * 4 + r4;
        attnb[(size_t)(b * 2048 + il) * 1024 + h * 64 + nd * 16 + fr] = (bf16)oacc[mf][nd][r4];
      }
}

extern "C" void kernel_launch(void* const* d_in, const int* in_sizes, int n_in,
                              void* d_out, int out_size, void* d_ws, size_t ws_size,
                              hipStream_t stream)
{
  const float* query = (const float*)d_in[0];
  const float* key   = (const float*)d_in[1];
  const float* value = (const float*)d_in[2];
  const float* Wq    = (const float*)d_in[3];
  const float* Wk    = (const float*)d_in[4];
  const float* Wv    = (const float*)d_in[5];
  const float* Wo    = (const float*)d_in[6];
  const float* bo    = (const float*)d_in[7];

  float* out = (float*)d_out;                 // 2*2048*1024 fp32
  float* P   = out + 4194304;                 // attn_weight: 2*16*2048*2048 fp32

  // --- scratch inside P (dead until attn_kernel writes it) ---
  bf16* qh  = (bf16*)(P + 0);
  bf16* ql  = (bf16*)(P + 2097152);
  bf16* kh  = (bf16*)(P + 4194304);
  bf16* kl  = (bf16*)(P + 6291456);
  bf16* wqh = (bf16*)(P + 8388608);
  bf16* wql = (bf16*)(P + 8912896);
  bf16* wkh = (bf16*)(P + 9437184);
  bf16* wkl = (bf16*)(P + 9961472);
  bf16* vb  = (bf16*)(P + 10485760);
  bf16* wvb = (bf16*)(P + 12582912);

  // --- persistent workspace ---
  float* ws   = (float*)d_ws;
  bf16* Qh_g  = (bf16*)(ws + 0);          // 4096x1024 bf16 each
  bf16* Ql_g  = (bf16*)(ws + 2097152);
  bf16* Kh_g  = (bf16*)(ws + 4194304);
  bf16* Kl_g  = (bf16*)(ws + 6291456);
  bf16* Vt_g  = (bf16*)(ws + 8388608);    // [(b*16+h)*64+d][2048]
  bf16* attnb = (bf16*)(ws + 10485760);   // 4096x1024 bf16
  bf16* wob   = (bf16*)(ws + 12582912);   // 1024x1024 bf16
  float* cmax = ws + 13107200;            // 32*2048
  float* csui = ws + 13172736;

  conv_kernel<<<16384, 256, 0, stream>>>(query, key, value, Wq, Wk, Wv, Wo,
                                         qh, ql, kh, kl, wqh, wql, wkh, wkl, vb, wvb, wob);
  projqk_kernel<<<dim3(256, 2), 256, 0, stream>>>(qh, ql, kh, kl, wqh, wql, wkh, wkl,
                                                  Qh_g, Ql_g, Kh_g, Kl_g);
  projv_kernel<<<256, 256, 0, stream>>>(vb, wvb, Vt_g);
  stats_kernel<<<512, 512, 0, stream>>>(Qh_g, Ql_g, Kh_g, Kl_g, cmax, csui);
  attn_kernel<<<512, 256, 0, stream>>>(Qh_g, Ql_g, Kh_g, Kl_g, Vt_g, cmax, csui, P, attnb);
  out_kernel<<<256, 256, 0, stream>>>(attnb, wob, bo, out);
}

// Round 12
// 369.684 us; speedup vs baseline: 1.0048x; 1.0048x over previous
//
#include <hip/hip_runtime.h>
#include <cmath>

typedef __bf16 bf16;
typedef __attribute__((ext_vector_type(4))) __bf16 bf16x4;
typedef __attribute__((ext_vector_type(8))) __bf16 bf16x8;
typedef __attribute__((ext_vector_type(4))) float f32x4;

#define MFMA16(a, b, c) __builtin_amdgcn_mfma_f32_16x16x32_bf16((a), (b), (c), 0, 0, 0)
#define SETPRIO1 __builtin_amdgcn_s_setprio(1)
#define SETPRIO0 __builtin_amdgcn_s_setprio(0)
#define EXP2(x) __builtin_amdgcn_exp2f(x)
#define SCHEDBAR __builtin_amdgcn_sched_barrier(0)
// fused waitcnt+barrier in ONE asm so no memory op can slip between them
#define WAITV_BAR(N) asm volatile("s_waitcnt vmcnt(" #N ")\n\ts_barrier" ::: "memory")
#define WAITL_BAR    asm volatile("s_waitcnt lgkmcnt(0)\n\ts_barrier" ::: "memory")

#define LOG2E 1.4426950408889634f

static __device__ __forceinline__ void gload16(const bf16* g, bf16* l)
{
  __builtin_amdgcn_global_load_lds((const __attribute__((address_space(1))) void*)g,
                                   (__attribute__((address_space(3))) void*)l, 16, 0, 0);
}

static __device__ __forceinline__ void split4(const float4 v, bf16x4& h, bf16x4& l)
{
  h[0] = (bf16)v.x; l[0] = (bf16)(v.x - (float)h[0]);
  h[1] = (bf16)v.y; l[1] = (bf16)(v.y - (float)h[1]);
  h[2] = (bf16)v.z; l[2] = (bf16)(v.z - (float)h[2]);
  h[3] = (bf16)v.w; l[3] = (bf16)(v.w - (float)h[3]);
}

// ---- conv: one-time fp32 -> bf16 (hi/lo or single) conversion of inputs/weights ----
__global__ __launch_bounds__(256) void conv_kernel(
    const float* __restrict__ query, const float* __restrict__ key, const float* __restrict__ value,
    const float* __restrict__ Wq, const float* __restrict__ Wk, const float* __restrict__ Wv,
    const float* __restrict__ Wo,
    bf16* __restrict__ qh, bf16* __restrict__ ql, bf16* __restrict__ kh, bf16* __restrict__ kl,
    bf16* __restrict__ wqh, bf16* __restrict__ wql, bf16* __restrict__ wkh, bf16* __restrict__ wkl,
    bf16* __restrict__ vb, bf16* __restrict__ wvb, bf16* __restrict__ wob)
{
  const int i = blockIdx.x * 256 + threadIdx.x;   // float4 index, 4,194,304 total
  const float* src;
  bf16 *dh, *dl;
  int e;
  if (i < 1048576)      { src = query; dh = qh; dl = ql; e = i; }
  else if (i < 2097152) { src = key;   dh = kh; dl = kl; e = i - 1048576; }
  else if (i < 3145728) { src = value; dh = vb; dl = nullptr; e = i - 2097152; }
  else {
    const int w = i - 3145728;
    const int which = w >> 18;
    e = w & 262143;
    src = (which == 0) ? Wq : (which == 1) ? Wk : (which == 2) ? Wv : Wo;
    dh  = (which == 0) ? wqh : (which == 1) ? wkh : (which == 2) ? wvb : wob;
    dl  = (which == 0) ? wql : (which == 1) ? wkl : nullptr;
  }
  const float4 v = ((const float4*)src)[e];
  bf16x4 h, l;
  split4(v, h, l);
  *(bf16x4*)(dh + (size_t)e * 4) = h;
  if (dl) *(bf16x4*)(dl + (size_t)e * 4) = l;
}

// ---- proj: y=0 Q / y=1 K (split-bf16 3-pass + fused RoPE), y=2 V (1-pass -> V^T) ----
// K output pre-scaled by 8*log2e so downstream softmax uses bare v_exp_f32 (2^x)
__global__ __launch_bounds__(256) void proj_kernel(
    const bf16* __restrict__ qh, const bf16* __restrict__ ql,
    const bf16* __restrict__ kh, const bf16* __restrict__ kl,
    const bf16* __restrict__ wqh, const bf16* __restrict__ wql,
    const bf16* __restrict__ wkh, const bf16* __restrict__ wkl,
    const bf16* __restrict__ vb, const bf16* __restrict__ wvb,
    bf16* __restrict__ Qh_g, bf16* __restrict__ Ql_g,
    bf16* __restrict__ Kh_g, bf16* __restrict__ Kl_g,
    bf16* __restrict__ Vt_g)
{
  __shared__ __align__(16) bf16 sm[2][4][4096];   // [buf][Ah,Al,Bh,Bl][128*32]
  const int tid = threadIdx.x, lane = tid & 63, w = tid >> 6;
  const int wm = w >> 1, wn = w & 1;
  const int fr = lane & 15, fg = lane >> 4;
  const int bm = blockIdx.x >> 3, bn = blockIdx.x & 7;
  const int lrow = lane >> 2, lcol = (lane & 3) * 8;
  const int which = blockIdx.y;

  if (which == 2) {
    // ---- V path: 1-pass bf16 GEMM; writes V^T per-head bf16 ----
    auto stageV = [&](int buf, int kt) {
#pragma unroll
      for (int q = 0; q < 2; ++q) {
        const int r = (q * 4 + w) * 16 + lrow;
        gload16(vb  + (size_t)(bm * 128 + r) * 1024 + kt * 32 + lcol, &sm[buf][0][(q * 4 + w) * 512]);
        gload16(wvb + (size_t)(bn * 128 + r) * 1024 + kt * 32 + lcol, &sm[buf][1][(q * 4 + w) * 512]);
      }
    };
    f32x4 acc[4][4] = {};
    stageV(0, 0);
    for (int kt = 0; kt < 32; ++kt) {
      const int cur = kt & 1;
      if (kt < 31) { stageV(cur ^ 1, kt + 1); WAITV_BAR(4); }
      else         { WAITV_BAR(0); }
      bf16x8 af[4], bf[4];
#pragma unroll
      for (int m = 0; m < 4; ++m) af[m] = *(bf16x8*)&sm[cur][0][(wm * 64 + m * 16 + fr) * 32 + fg * 8];
#pragma unroll
      for (int n = 0; n < 4; ++n) bf[n] = *(bf16x8*)&sm[cur][1][(wn * 64 + n * 16 + fr) * 32 + fg * 8];
      SETPRIO1;
#pragma unroll
      for (int m = 0; m < 4; ++m)
#pragma unroll
        for (int n = 0; n < 4; ++n) acc[m][n] = MFMA16(af[m], bf[n], acc[m][n]);
      SETPRIO0;
      WAITL_BAR;
    }
#pragma unroll
    for (int m = 0; m < 4; ++m) {
      const int row0 = bm * 128 + wm * 64 + m * 16 + fg * 4;
      const int b = row0 >> 11, l0 = row0 & 2047;
#pragma unroll
      for (int n = 0; n < 4; ++n) {
        const int col = bn * 128 + wn * 64 + n * 16 + fr;
        const int h = col >> 6, d = col & 63;
        bf16x4 pk;
#pragma unroll
        for (int j = 0; j < 4; ++j) pk[j] = (bf16)acc[m][n][j];
        *(bf16x4*)(Vt_g + ((size_t)((b * 16 + h) * 64 + d)) * 2048 + l0) = pk;
      }
    }
    return;
  }

  // ---- Q/K path: split-bf16 3-pass, fused RoPE epilogue ----
  const bf16* ta[4];
  ta[0] = which ? kh : qh;   ta[1] = which ? kl : ql;
  ta[2] = which ? wkh : wqh; ta[3] = which ? wkl : wql;
  bf16* oh = which ? Kh_g : Qh_g;
  bf16* ol = which ? Kl_g : Ql_g;
  const float oscale = which ? 8.0f * LOG2E : 1.0f;
  const int rb[4] = {bm * 128, bm * 128, bn * 128, bn * 128};

  auto stage = [&](int buf, int kt) {
#pragma unroll
    for (int tl = 0; tl < 4; ++tl)
#pragma unroll
      for (int q = 0; q < 2; ++q) {
        const int r = (q * 4 + w) * 16 + lrow;
        gload16(ta[tl] + (size_t)(rb[tl] + r) * 1024 + kt * 32 + lcol,
                &sm[buf][tl][(q * 4 + w) * 512]);
      }
  };

  f32x4 acc[4][4] = {};
  stage(0, 0);
  for (int kt = 0; kt < 32; ++kt) {
    const int cur = kt & 1;
    if (kt < 31) { stage(cur ^ 1, kt + 1); WAITV_BAR(8); }
    else         { WAITV_BAR(0); }
    bf16x8 afh[4], afl[4], bfh[4], bfl[4];
#pragma unroll
    for (int m = 0; m < 4; ++m) {
      afh[m] = *(bf16x8*)&sm[cur][0][(wm * 64 + m * 16 + fr) * 32 + fg * 8];
      afl[m] = *(bf16x8*)&sm[cur][1][(wm * 64 + m * 16 + fr) * 32 + fg * 8];
    }
#pragma unroll
    for (int n = 0; n < 4; ++n) {
      bfh[n] = *(bf16x8*)&sm[cur][2][(wn * 64 + n * 16 + fr) * 32 + fg * 8];
      bfl[n] = *(bf16x8*)&sm[cur][3][(wn * 64 + n * 16 + fr) * 32 + fg * 8];
    }
    SETPRIO1;
#pragma unroll
    for (int m = 0; m < 4; ++m)
#pragma unroll
      for (int n = 0; n < 4; ++n) {
        acc[m][n] = MFMA16(afh[m], bfh[n], acc[m][n]);
        acc[m][n] = MFMA16(afh[m], bfl[n], acc[m][n]);
        acc[m][n] = MFMA16(afl[m], bfh[n], acc[m][n]);
      }
    SETPRIO0;
    WAITL_BAR;
  }
  // epilogue: RoPE (first 32 dims of each head, interleaved pairs), scale, split, store
#pragma unroll
  for (int n = 0; n < 4; ++n) {
    const int d = n * 16 + fr;
    const bool rot = (n < 2);
    const float invf = rot ? exp2f((float)(d >> 1) * (-0.83048202372184059f)) : 0.0f;
    const int odd = d & 1;
    const int col = bn * 128 + wn * 64 + n * 16 + fr;
#pragma unroll
    for (int m = 0; m < 4; ++m)
#pragma unroll
      for (int r4 = 0; r4 < 4; ++r4) {
        const int row = bm * 128 + wm * 64 + m * 16 + fg * 4 + r4;
        float x = acc[m][n][r4];
        const float p = __shfl_xor(x, 1);
        if (rot) {
          float sn, cs;
          sincosf((float)(row & 2047) * invf, &sn, &cs);
          x = odd ? x * cs + p * sn : x * cs - p * sn;
        }
        x *= oscale;
        const bf16 hv = (bf16)x;
        oh[(size_t)row * 1024 + col] = hv;
        ol[(size_t)row * 1024 + col] = (bf16)(x - (float)hv);
      }
  }
}

// ---- out: 1-pass bf16 GEMM, gload_lds dbuf; + bias -> fp32 ----
__global__ __launch_bounds__(256) void out_kernel(const bf16* __restrict__ attnb,
                                                  const bf16* __restrict__ wob,
                                                  const float* __restrict__ bo,
                                                  float* __restrict__ out)
{
  __shared__ __align__(16) bf16 sm[2][2][4096];
  const int tid = threadIdx.x, lane = tid & 63, w = tid >> 6;
  const int wm = w >> 1, wn = w & 1;
  const int fr = lane & 15, fg = lane >> 4;
  const int bm = blockIdx.x >> 3, bn = blockIdx.x & 7;
  const int lrow = lane >> 2, lcol = (lane & 3) * 8;

  auto stage = [&](int buf, int kt) {
#pragma unroll
    for (int q = 0; q < 2; ++q) {
      const int r = (q * 4 + w) * 16 + lrow;
      gload16(attnb + (size_t)(bm * 128 + r) * 1024 + kt * 32 + lcol, &sm[buf][0][(q * 4 + w) * 512]);
      gload16(wob   + (size_t)(bn * 128 + r) * 1024 + kt * 32 + lcol, &sm[buf][1][(q * 4 + w) * 512]);
    }
  };

  f32x4 acc[4][4] = {};
  stage(0, 0);
  for (int kt = 0; kt < 32; ++kt) {
    const int cur = kt & 1;
    if (kt < 31) { stage(cur ^ 1, kt + 1); WAITV_BAR(4); }
    else         { WAITV_BAR(0); }
    bf16x8 af[4], bf[4];
#pragma unroll
    for (int m = 0; m < 4; ++m) af[m] = *(bf16x8*)&sm[cur][0][(wm * 64 + m * 16 + fr) * 32 + fg * 8];
#pragma unroll
    for (int n = 0; n < 4; ++n) bf[n] = *(bf16x8*)&sm[cur][1][(wn * 64 + n * 16 + fr) * 32 + fg * 8];
    SETPRIO1;
#pragma unroll
    for (int m = 0; m < 4; ++m)
#pragma unroll
      for (int n = 0; n < 4; ++n) acc[m][n] = MFMA16(af[m], bf[n], acc[m][n]);
    SETPRIO0;
    WAITL_BAR;
  }
#pragma unroll
  for (int m = 0; m < 4; ++m)
#pragma unroll
    for (int n = 0; n < 4; ++n) {
      const int col = bn * 128 + wn * 64 + n * 16 + fr;
      const float bv = bo[col];
#pragma unroll
      for (int r4 = 0; r4 < 4; ++r4) {
        const int row = bm * 128 + wm * 64 + m * 16 + fg * 4 + r4;
        out[(size_t)row * 1024 + col] = acc[m][n][r4] + bv;
      }
    }
}

// ---- stats: per-(b,h,j) column max (log2 domain) + reciprocal sum of exp2 ----
__global__ __launch_bounds__(512) void stats_kernel(const bf16* __restrict__ Qh_g, const bf16* __restrict__ Ql_g,
                                                    const bf16* __restrict__ Kh_g, const bf16* __restrict__ Kl_g,
                                                    float* __restrict__ colmax, float* __restrict__ csuminv)
{
  __shared__ __align__(16) bf16 smh[2][8192], sml[2][8192];   // [buf][128*64], K staged via buf1
  const int swz = (blockIdx.x & 7) * 64 + (blockIdx.x >> 3);
  const int bh = swz >> 4, jb = swz & 15;
  const int b = bh >> 4, h = bh & 15;
  const int t = threadIdx.x, lane = t & 63, w = t >> 6;
  const int fr = lane & 15, fg = lane >> 4;
  const int lr = lane >> 3, lc = lane & 7;

  auto stageQ = [&](int buf, int it) {
#pragma unroll
    for (int q = 0; q < 2; ++q) {
      const int r = (q * 8 + w) * 8 + lr;
      const size_t g = (size_t)(b * 2048 + it * 128 + r) * 1024 + h * 64 + ((lc ^ (r & 7)) * 8);
      gload16(Qh_g + g, &smh[buf][(q * 8 + w) * 512]);
      gload16(Ql_g + g, &sml[buf][(q * 8 + w) * 512]);
    }
  };

  // stage K into buf1 (4 ops), then Q it=0 into buf0 (4 ops)
#pragma unroll
  for (int q = 0; q < 2; ++q) {
    const int r = (q * 8 + w) * 8 + lr;
    const size_t g = (size_t)(b * 2048 + jb * 128 + r) * 1024 + h * 64 + ((lc ^ (r & 7)) * 8);
    gload16(Kh_g + g, &smh[1][(q * 8 + w) * 512]);
    gload16(Kl_g + g, &sml[1][(q * 8 + w) * 512]);
  }
  stageQ(0, 0);
  WAITV_BAR(4);              // K done (Q0 still in flight)
  bf16x8 kfh[2], kfl[2];
#pragma unroll
  for (int ks = 0; ks < 2; ++ks) {
    const int rr = w * 16 + fr;
    const int cc = (ks * 32 + fg * 8) ^ ((rr & 7) << 3);
    kfh[ks] = *(bf16x8*)&smh[1][rr * 64 + cc];
    kfl[ks] = *(bf16x8*)&sml[1][rr * 64 + cc];
  }
  WAITL_BAR;                 // K frag reads done -> buf1 reusable

  float rm[4] = {-1e30f, -1e30f, -1e30f, -1e30f};
  float rs[4] = {0.f, 0.f, 0.f, 0.f};
  for (int it = 0; it < 16; ++it) {
    const int cur = it & 1;
    if (it < 15) { stageQ(cur ^ 1, it + 1); WAITV_BAR(4); }
    else         { WAITV_BAR(0); }
    f32x4 acc[8] = {};
    SETPRIO1;
#pragma unroll
    for (int ks = 0; ks < 2; ++ks)
#pragma unroll
      for (int n = 0; n < 8; ++n) {
        const int rr = n * 16 + fr;
        const int cc = (ks * 32 + fg * 8) ^ ((rr & 7) << 3);
        const bf16x8 qf = *(bf16x8*)&smh[cur][rr * 64 + cc];
        const bf16x8 lf = *(bf16x8*)&sml[cur][rr * 64 + cc];
        acc[n] = MFMA16(kfh[ks], qf, acc[n]);
        acc[n] = MFMA16(kfh[ks], lf, acc[n]);
        acc[n] = MFMA16(kfl[ks], qf, acc[n]);
      }
    SETPRIO0;
    // per-lane online update (no cross-lane ops in the loop)
#pragma unroll
    for (int r4 = 0; r4 < 4; ++r4) {
      const float m = fmaxf(fmaxf(fmaxf(acc[0][r4], acc[1][r4]), fmaxf(acc[2][r4], acc[3][r4])),
                            fmaxf(fmaxf(acc[4][r4], acc[5][r4]), fmaxf(acc[6][r4], acc[7][r4])));
      const float mn = fmaxf(rm[r4], m);
      float ts = 0.f;
#pragma unroll
      for (int n = 0; n < 8; ++n) ts += EXP2(acc[n][r4] - mn);
      rs[r4] = rs[r4] * EXP2(rm[r4] - mn) + ts;
      rm[r4] = mn;
    }
    WAITL_BAR;
  }
  // cross-lane combine: the 16 lanes varying fr share the same j
#pragma unroll
  for (int r4 = 0; r4 < 4; ++r4) {
    float M = rm[r4];
#pragma unroll
    for (int off = 1; off < 16; off <<= 1) M = fmaxf(M, __shfl_xor(M, off));
    float s = rs[r4] * EXP2(rm[r4] - M);
#pragma unroll
    for (int off = 1; off < 16; off <<= 1) s += __shfl_xor(s, off);
    rm[r4] = M;
    rs[r4] = s;
  }
  if (fr == 0) {
#pragma unroll
    for (int r4 = 0; r4 < 4; ++r4) {
      const int j = jb * 128 + w * 16 + fg * 4 + r4;
      colmax[bh * 2048 + j] = rm[r4];
      csuminv[bh * 2048 + j] = 1.0f / rs[r4];
    }
  }
}

// ---- attn: gload_lds double-buffered K/V staging (XOR swizzle), counted vmcnt ----
__global__ __launch_bounds__(256) void attn_kernel(const bf16* __restrict__ Qh_g, const bf16* __restrict__ Ql_g,
                                                   const bf16* __restrict__ Kh_g, const bf16* __restrict__ Kl_g,
                                                   const bf16* __restrict__ Vt_g,
                                                   const float* __restrict__ colmax, const float* __restrict__ csuminv,
                                                   float* __restrict__ P, bf16* __restrict__ attnb)
{
  // layout: dbuf [2][3][64*64] bf16 = 48KB at 0 (Kh,Kl,Vt per buf); Pb [128][72] at 49152
  __shared__ __align__(16) unsigned char smem[67584];
  bf16(*Pb)[72] = (bf16(*)[72])(smem + 49152);
  bf16(*Qh)[72] = (bf16(*)[72])smem;                  // overlay: 128 rows (prologue only)
  bf16(*Ql)[72] = (bf16(*)[72])(smem + 18432);

  const int swz = (blockIdx.x & 7) * 64 + (blockIdx.x >> 3);
  const int bh = swz >> 4, ib = swz & 15;
  const int b = bh >> 4, h = bh & 15;
  const int t = threadIdx.x, lane = t & 63, w = t >> 6;
  const int fr = lane & 15, fg = lane >> 4;

  // prologue: stage Q i-block (padded overlay) and preload fragments
#pragma unroll
  for (int q = 0; q < 4; ++q) {
    const int u = q * 256 + t, r = u >> 3, c8 = (u & 7) * 8;
    const size_t g = (size_t)(b * 2048 + ib * 128 + r) * 1024 + h * 64 + c8;
    *(bf16x8*)&Qh[r][c8] = *(const bf16x8*)(Qh_g + g);
    *(bf16x8*)&Ql[r][c8] = *(const bf16x8*)(Ql_g + g);
  }
  WAITL_BAR;
  bf16x8 qfh[2][2], qfl[2][2];
#pragma unroll
  for (int mf = 0; mf < 2; ++mf)
#pragma unroll
    for (int ks = 0; ks < 2; ++ks) {
      qfh[mf][ks] = *(bf16x8*)&Qh[w * 32 + mf * 16 + fr][ks * 32 + fg * 8];
      qfl[mf][ks] = *(bf16x8*)&Ql[w * 32 + mf * 16 + fr][ks * 32 + fg * 8];
    }
  WAITL_BAR;       // all waves done reading Q overlay -> dbuf region free

  // K/V tile stage: direct-to-LDS, source chunks pre-swizzled (chunk ^ (row&7))
  auto stage = [&](int buf, int jt1) {
    bf16* base = (bf16*)(smem + buf * 24576);
#pragma unroll
    for (int q = 0; q < 2; ++q) {
      const int u = q * 256 + t, r = u >> 3, lc = u & 7;
      const int sc = (lc ^ (r & 7)) * 8;
      const size_t gk = (size_t)(b * 2048 + jt1 * 64 + r) * 1024 + h * 64 + sc;
      gload16(Kh_g + gk, base + u * 8);
      gload16(Kl_g + gk, base + 4096 + u * 8);
      gload16(Vt_g + (size_t)(bh * 64 + r) * 2048 + jt1 * 64 + sc, base + 8192 + u * 8);
    }
  };

  stage(0, 0);
  WAITV_BAR(0);    // tile 0 ready

  f32x4 oacc[2][4] = {};
  for (int jt = 0; jt < 32; ++jt) {
    const int cur = jt & 1;
    bf16* bufK  = (bf16*)(smem + cur * 24576);
    bf16* bufKl = bufK + 4096;
    bf16* bufV  = bufK + 8192;
    // stats loads: consumed at exp phase (compiler-managed wait, hides under S-MFMA)
    float cmr[4], rcr[4];
#pragma unroll
    for (int nj = 0; nj < 4; ++nj) {
      const int jg = jt * 64 + nj * 16 + fr;
      cmr[nj] = colmax[bh * 2048 + jg];
      rcr[nj] = csuminv[bh * 2048 + jg];
    }
    // S tile = Q . K^T (scaled by 8*log2e via K); swizzled LDS reads
    f32x4 s[2][4] = {};
    SETPRIO1;
#pragma unroll
    for (int ks = 0; ks < 2; ++ks)
#pragma unroll
      for (int nj = 0; nj < 4; ++nj) {
        const int rr = nj * 16 + fr;
        const int cc = ((ks * 4 + fg) ^ (rr & 7)) * 8;
        const bf16x8 khf = *(bf16x8*)(bufK + rr * 64 + cc);
        const bf16x8 klf = *(bf16x8*)(bufKl + rr * 64 + cc);
#pragma unroll
        for (int mf = 0; mf < 2; ++mf) {
          s[mf][nj] = MFMA16(qfh[mf][ks], khf, s[mf][nj]);
          s[mf][nj] = MFMA16(qfh[mf][ks], klf, s[mf][nj]);
          s[mf][nj] = MFMA16(qfl[mf][ks], khf, s[mf][nj]);
        }
      }
    SETPRIO0;
    // normalize in place (s := P) and stash bf16 copy in LDS
#pragma unroll
    for (int nj = 0; nj < 4; ++nj)
#pragma unroll
      for (int mf = 0; mf < 2; ++mf)
#pragma unroll
        for (int r4 = 0; r4 < 4; ++r4) {
          const int il = w * 32 + mf * 16 + fg * 4 + r4;
          const float pv = EXP2(s[mf][nj][r4] - cmr[nj]) * rcr[nj];
          s[mf][nj][r4] = pv;
          Pb[il][nj * 16 + fr] = (bf16)pv;
        }
    WAITL_BAR;     // BAR1: Pb visible; all waves past iter jt-1 entirely -> buf[cur^1] free
    if (jt < 31) stage(cur ^ 1, jt + 1);   // 6 loads, pinned before the P stores
    SCHEDBAR;
    // P global stores (32 scalar): overlap PV; newest vmem ops for the counted wait
#pragma unroll
    for (int nj = 0; nj < 4; ++nj) {
      const int jg = jt * 64 + nj * 16 + fr;
#pragma unroll
      for (int mf = 0; mf < 2; ++mf)
#pragma unroll
        for (int r4 = 0; r4 < 4; ++r4) {
          const int il = w * 32 + mf * 16 + fg * 4 + r4;
          P[(size_t)(bh * 2048 + ib * 128 + il) * 2048 + jg] = s[mf][nj][r4];
        }
    }
    SETPRIO1;
#pragma unroll
    for (int ks = 0; ks < 2; ++ks) {
      bf16x8 pa[2];
#pragma unroll
      for (int mf = 0; mf < 2; ++mf) pa[mf] = *(bf16x8*)&Pb[w * 32 + mf * 16 + fr][ks * 32 + fg * 8];
#pragma unroll
      for (int nd = 0; nd < 4; ++nd) {
        const int rr = nd * 16 + fr;
        const int cc = ((ks * 4 + fg) ^ (rr & 7)) * 8;
        const bf16x8 vbf = *(bf16x8*)(bufV + rr * 64 + cc);
#pragma unroll
        for (int mf = 0; mf < 2; ++mf) oacc[mf][nd] = MFMA16(pa[mf], vbf, oacc[mf][nd]);
      }
    }
    SETPRIO0;
    // end-bar: vmcnt(32) = keep only the 32 P stores in flight -> stage drained
    if (jt < 31) { WAITV_BAR(32); }
  }
#pragma unroll
  for (int mf = 0; mf < 2; ++mf)
#pragma unroll
    for (int nd = 0; nd < 4; ++nd)
#pragma unroll
      for (int r4 = 0; r4 < 4; ++r4) {
        const int il = ib * 128 + w * 32 + mf * 16 + fg * 4 + r4;
        attnb[(size_t)(b * 2048 + il) * 1024 + h * 64 + nd * 16 + fr] = (bf16)oacc[mf][nd][r4];
      }
}

extern "C" void kernel_launch(void* const* d_in, const int* in_sizes, int n_in,
                              void* d_out, int out_size, void* d_ws, size_t ws_size,
                              hipStream_t stream)
{
  const float* query = (const float*)d_in[0];
  const float* key   = (const float*)d_in[1];
  const float* value = (const float*)d_in[2];
  const float* Wq    = (const float*)d_in[3];
  const float* Wk    = (const float*)d_in[4];
  const float* Wv    = (const float*)d_in[5];
  const float* Wo    = (const float*)d_in[6];
  const float* bo    = (const float*)d_in[7];

  float* out = (float*)d_out;                 // 2*2048*1024 fp32
  float* P   = out + 4194304;                 // attn_weight: 2*16*2048*2048 fp32

  // --- scratch inside P (dead until attn_kernel writes it) ---
  bf16* qh  = (bf16*)(P + 0);
  bf16* ql  = (bf16*)(P + 2097152);
  bf16* kh  = (bf16*)(P + 4194304);
  bf16* kl  = (bf16*)(P + 6291456);
  bf16* wqh = (bf16*)(P + 8388608);
  bf16* wql = (bf16*)(P + 8912896);
  bf16* wkh = (bf16*)(P + 9437184);
  bf16* wkl = (bf16*)(P + 9961472);
  bf16* vb  = (bf16*)(P + 10485760);
  bf16* wvb = (bf16*)(P + 12582912);

  // --- persistent workspace ---
  float* ws   = (float*)d_ws;
  bf16* Qh_g  = (bf16*)(ws + 0);          // 4096x1024 bf16 each
  bf16* Ql_g  = (bf16*)(ws + 2097152);
  bf16* Kh_g  = (bf16*)(ws + 4194304);
  bf16* Kl_g  = (bf16*)(ws + 6291456);
  bf16* Vt_g  = (bf16*)(ws + 8388608);    // [(b*16+h)*64+d][2048]
  bf16* attnb = (bf16*)(ws + 10485760);   // 4096x1024 bf16
  bf16* wob   = (bf16*)(ws + 12582912);   // 1024x1024 bf16
  float* cmax = ws + 13107200;            // 32*2048
  float* csui = ws + 13172736;

  conv_kernel<<<16384, 256, 0, stream>>>(query, key, value, Wq, Wk, Wv, Wo,
                                         qh, ql, kh, kl, wqh, wql, wkh, wkl, vb, wvb, wob);
  proj_kernel<<<dim3(256, 3), 256, 0, stream>>>(qh, ql, kh, kl, wqh, wql, wkh, wkl, vb, wvb,
                                                Qh_g, Ql_g, Kh_g, Kl_g, Vt_g);
  stats_kernel<<<512, 512, 0, stream>>>(Qh_g, Ql_g, Kh_g, Kl_g, cmax, csui);
  attn_kernel<<<512, 256, 0, stream>>>(Qh_g, Ql_g, Kh_g, Kl_g, Vt_g, cmax, csui, P, attnb);
  out_kernel<<<256, 256, 0, stream>>>(attnb, wob, bo, out);
}

// Round 13
// 337.036 us; speedup vs baseline: 1.1021x; 1.0969x over previous
//
#include <hip/hip_runtime.h>
#include <cmath>

typedef __bf16 bf16;
typedef __attribute__((ext_vector_type(4))) __bf16 bf16x4;
typedef __attribute__((ext_vector_type(8))) __bf16 bf16x8;
typedef __attribute__((ext_vector_type(4))) float f32x4;

#define MFMA16(a, b, c) __builtin_amdgcn_mfma_f32_16x16x32_bf16((a), (b), (c), 0, 0, 0)
#define SETPRIO1 __builtin_amdgcn_s_setprio(1)
#define SETPRIO0 __builtin_amdgcn_s_setprio(0)
#define EXP2(x) __builtin_amdgcn_exp2f(x)
#define SCHEDBAR __builtin_amdgcn_sched_barrier(0)
// fused waitcnt+barrier in ONE asm so no memory op can slip between them
#define WAITV_BAR(N) asm volatile("s_waitcnt vmcnt(" #N ")\n\ts_barrier" ::: "memory")
#define WAITL_BAR    asm volatile("s_waitcnt lgkmcnt(0)\n\ts_barrier" ::: "memory")

#define LOG2E 1.4426950408889634f

static __device__ __forceinline__ void gload16(const bf16* g, bf16* l)
{
  __builtin_amdgcn_global_load_lds((const __attribute__((address_space(1))) void*)g,
                                   (__attribute__((address_space(3))) void*)l, 16, 0, 0);
}

static __device__ __forceinline__ void split4(const float4 v, bf16x4& h, bf16x4& l)
{
  h[0] = (bf16)v.x; l[0] = (bf16)(v.x - (float)h[0]);
  h[1] = (bf16)v.y; l[1] = (bf16)(v.y - (float)h[1]);
  h[2] = (bf16)v.z; l[2] = (bf16)(v.z - (float)h[2]);
  h[3] = (bf16)v.w; l[3] = (bf16)(v.w - (float)h[3]);
}

// ---- conv: one-time fp32 -> bf16 (hi/lo or single) conversion of inputs/weights ----
__global__ __launch_bounds__(256) void conv_kernel(
    const float* __restrict__ query, const float* __restrict__ key, const float* __restrict__ value,
    const float* __restrict__ Wq, const float* __restrict__ Wk, const float* __restrict__ Wv,
    const float* __restrict__ Wo,
    bf16* __restrict__ qh, bf16* __restrict__ ql, bf16* __restrict__ kh, bf16* __restrict__ kl,
    bf16* __restrict__ wqh, bf16* __restrict__ wql, bf16* __restrict__ wkh, bf16* __restrict__ wkl,
    bf16* __restrict__ vb, bf16* __restrict__ wvb, bf16* __restrict__ wob)
{
  const int i = blockIdx.x * 256 + threadIdx.x;   // float4 index, 4,194,304 total
  const float* src;
  bf16 *dh, *dl;
  int e;
  if (i < 1048576)      { src = query; dh = qh; dl = ql; e = i; }
  else if (i < 2097152) { src = key;   dh = kh; dl = kl; e = i - 1048576; }
  else if (i < 3145728) { src = value; dh = vb; dl = nullptr; e = i - 2097152; }
  else {
    const int w = i - 3145728;
    const int which = w >> 18;
    e = w & 262143;
    src = (which == 0) ? Wq : (which == 1) ? Wk : (which == 2) ? Wv : Wo;
    dh  = (which == 0) ? wqh : (which == 1) ? wkh : (which == 2) ? wvb : wob;
    dl  = (which == 0) ? wql : (which == 1) ? wkl : nullptr;
  }
  const float4 v = ((const float4*)src)[e];
  bf16x4 h, l;
  split4(v, h, l);
  *(bf16x4*)(dh + (size_t)e * 4) = h;
  if (dl) *(bf16x4*)(dl + (size_t)e * 4) = l;
}

// ---- proj: y=0 Q / y=1 K (split-bf16 3-pass + fused RoPE), y=2 V (1-pass -> V^T) ----
// K output pre-scaled by 8*log2e so downstream softmax uses bare v_exp_f32 (2^x)
__global__ __launch_bounds__(256) void proj_kernel(
    const bf16* __restrict__ qh, const bf16* __restrict__ ql,
    const bf16* __restrict__ kh, const bf16* __restrict__ kl,
    const bf16* __restrict__ wqh, const bf16* __restrict__ wql,
    const bf16* __restrict__ wkh, const bf16* __restrict__ wkl,
    const bf16* __restrict__ vb, const bf16* __restrict__ wvb,
    bf16* __restrict__ Qh_g, bf16* __restrict__ Ql_g,
    bf16* __restrict__ Kh_g, bf16* __restrict__ Kl_g,
    bf16* __restrict__ Vt_g)
{
  __shared__ __align__(16) bf16 sm[2][4][4096];   // [buf][Ah,Al,Bh,Bl][128*32]
  const int tid = threadIdx.x, lane = tid & 63, w = tid >> 6;
  const int wm = w >> 1, wn = w & 1;
  const int fr = lane & 15, fg = lane >> 4;
  const int bm = blockIdx.x >> 3, bn = blockIdx.x & 7;
  const int lrow = lane >> 2, lcol = (lane & 3) * 8;
  const int which = blockIdx.y;

  if (which == 2) {
    // ---- V path: 1-pass bf16 GEMM; writes V^T per-head bf16 ----
    auto stageV = [&](int buf, int kt) {
#pragma unroll
      for (int q = 0; q < 2; ++q) {
        const int r = (q * 4 + w) * 16 + lrow;
        gload16(vb  + (size_t)(bm * 128 + r) * 1024 + kt * 32 + lcol, &sm[buf][0][(q * 4 + w) * 512]);
        gload16(wvb + (size_t)(bn * 128 + r) * 1024 + kt * 32 + lcol, &sm[buf][1][(q * 4 + w) * 512]);
      }
    };
    f32x4 acc[4][4] = {};
    stageV(0, 0);
    for (int kt = 0; kt < 32; ++kt) {
      const int cur = kt & 1;
      if (kt < 31) { stageV(cur ^ 1, kt + 1); WAITV_BAR(4); }
      else         { WAITV_BAR(0); }
      bf16x8 af[4], bf[4];
#pragma unroll
      for (int m = 0; m < 4; ++m) af[m] = *(bf16x8*)&sm[cur][0][(wm * 64 + m * 16 + fr) * 32 + fg * 8];
#pragma unroll
      for (int n = 0; n < 4; ++n) bf[n] = *(bf16x8*)&sm[cur][1][(wn * 64 + n * 16 + fr) * 32 + fg * 8];
      SETPRIO1;
#pragma unroll
      for (int m = 0; m < 4; ++m)
#pragma unroll
        for (int n = 0; n < 4; ++n) acc[m][n] = MFMA16(af[m], bf[n], acc[m][n]);
      SETPRIO0;
      WAITL_BAR;
    }
#pragma unroll
    for (int m = 0; m < 4; ++m) {
      const int row0 = bm * 128 + wm * 64 + m * 16 + fg * 4;
      const int b = row0 >> 11, l0 = row0 & 2047;
#pragma unroll
      for (int n = 0; n < 4; ++n) {
        const int col = bn * 128 + wn * 64 + n * 16 + fr;
        const int h = col >> 6, d = col & 63;
        bf16x4 pk;
#pragma unroll
        for (int j = 0; j < 4; ++j) pk[j] = (bf16)acc[m][n][j];
        *(bf16x4*)(Vt_g + ((size_t)((b * 16 + h) * 64 + d)) * 2048 + l0) = pk;
      }
    }
    return;
  }

  // ---- Q/K path: split-bf16 3-pass, fused RoPE epilogue ----
  const bf16* ta[4];
  ta[0] = which ? kh : qh;   ta[1] = which ? kl : ql;
  ta[2] = which ? wkh : wqh; ta[3] = which ? wkl : wql;
  bf16* oh = which ? Kh_g : Qh_g;
  bf16* ol = which ? Kl_g : Ql_g;
  const float oscale = which ? 8.0f * LOG2E : 1.0f;
  const int rb[4] = {bm * 128, bm * 128, bn * 128, bn * 128};

  auto stage = [&](int buf, int kt) {
#pragma unroll
    for (int tl = 0; tl < 4; ++tl)
#pragma unroll
      for (int q = 0; q < 2; ++q) {
        const int r = (q * 4 + w) * 16 + lrow;
        gload16(ta[tl] + (size_t)(rb[tl] + r) * 1024 + kt * 32 + lcol,
                &sm[buf][tl][(q * 4 + w) * 512]);
      }
  };

  f32x4 acc[4][4] = {};
  stage(0, 0);
  for (int kt = 0; kt < 32; ++kt) {
    const int cur = kt & 1;
    if (kt < 31) { stage(cur ^ 1, kt + 1); WAITV_BAR(8); }
    else         { WAITV_BAR(0); }
    bf16x8 afh[4], afl[4], bfh[4], bfl[4];
#pragma unroll
    for (int m = 0; m < 4; ++m) {
      afh[m] = *(bf16x8*)&sm[cur][0][(wm * 64 + m * 16 + fr) * 32 + fg * 8];
      afl[m] = *(bf16x8*)&sm[cur][1][(wm * 64 + m * 16 + fr) * 32 + fg * 8];
    }
#pragma unroll
    for (int n = 0; n < 4; ++n) {
      bfh[n] = *(bf16x8*)&sm[cur][2][(wn * 64 + n * 16 + fr) * 32 + fg * 8];
      bfl[n] = *(bf16x8*)&sm[cur][3][(wn * 64 + n * 16 + fr) * 32 + fg * 8];
    }
    SETPRIO1;
#pragma unroll
    for (int m = 0; m < 4; ++m)
#pragma unroll
      for (int n = 0; n < 4; ++n) {
        acc[m][n] = MFMA16(afh[m], bfh[n], acc[m][n]);
        acc[m][n] = MFMA16(afh[m], bfl[n], acc[m][n]);
        acc[m][n] = MFMA16(afl[m], bfh[n], acc[m][n]);
      }
    SETPRIO0;
    WAITL_BAR;
  }
  // epilogue: RoPE, scale, split, store. Loop order (m,r4) outer / n inner so the
  // 4 column-stores per fixed row fold into offset: immediates (cols 32B apart).
#pragma unroll
  for (int m = 0; m < 4; ++m)
#pragma unroll
    for (int r4 = 0; r4 < 4; ++r4) {
      const int row = bm * 128 + wm * 64 + m * 16 + fg * 4 + r4;
      const size_t rbase = (size_t)row * 1024 + bn * 128 + wn * 64 + fr;
      float sn[2], cs[2];
#pragma unroll
      for (int n = 0; n < 2; ++n) {
        const int d = n * 16 + fr;
        const float invf = exp2f((float)(d >> 1) * (-0.83048202372184059f));
        sincosf((float)(row & 2047) * invf, &sn[n], &cs[n]);
      }
#pragma unroll
      for (int n = 0; n < 4; ++n) {
        float x = acc[m][n][r4];
        const float p = __shfl_xor(x, 1);
        if (n < 2) {
          const int odd = fr & 1;
          x = odd ? x * cs[n] + p * sn[n] : x * cs[n] - p * sn[n];
        }
        x *= oscale;
        const bf16 hv = (bf16)x;
        oh[rbase + n * 16] = hv;
        ol[rbase + n * 16] = (bf16)(x - (float)hv);
      }
    }
}

// ---- out: 1-pass bf16 GEMM, 128x64 tiles (512 blocks -> 2 blocks/CU); + bias ----
__global__ __launch_bounds__(256) void out_kernel(const bf16* __restrict__ attnb,
                                                  const bf16* __restrict__ wob,
                                                  const float* __restrict__ bo,
                                                  float* __restrict__ out)
{
  __shared__ __align__(16) bf16 sm[2][6144];   // [buf][A 128x32 | B 64x32]
  const int tid = threadIdx.x, lane = tid & 63, w = tid >> 6;
  const int wm = w >> 1, wn = w & 1;           // wave grid 2x2 over 128x64
  const int fr = lane & 15, fg = lane >> 4;
  const int bm = blockIdx.x >> 4, bn = blockIdx.x & 15;
  const int lrow = lane >> 2, lcol = (lane & 3) * 8;

  auto stage = [&](int buf, int kt) {
#pragma unroll
    for (int q = 0; q < 2; ++q) {   // A: 128 rows
      const int r = (q * 4 + w) * 16 + lrow;
      gload16(attnb + (size_t)(bm * 128 + r) * 1024 + kt * 32 + lcol, &sm[buf][(q * 4 + w) * 512]);
    }
    {                               // B: 64 rows (waves 0-3 each 16 rows)
      const int r = w * 16 + lrow;
      gload16(wob + (size_t)(bn * 64 + r) * 1024 + kt * 32 + lcol, &sm[buf][4096 + w * 512]);
    }
  };

  f32x4 acc[4][2] = {};
  stage(0, 0);
  for (int kt = 0; kt < 32; ++kt) {
    const int cur = kt & 1;
    if (kt < 31) { stage(cur ^ 1, kt + 1); WAITV_BAR(3); }
    else         { WAITV_BAR(0); }
    bf16x8 af[4], bf[2];
#pragma unroll
    for (int m = 0; m < 4; ++m) af[m] = *(bf16x8*)&sm[cur][(wm * 64 + m * 16 + fr) * 32 + fg * 8];
#pragma unroll
    for (int n = 0; n < 2; ++n) bf[n] = *(bf16x8*)&sm[cur][4096 + (wn * 32 + n * 16 + fr) * 32 + fg * 8];
    SETPRIO1;
#pragma unroll
    for (int m = 0; m < 4; ++m)
#pragma unroll
      for (int n = 0; n < 2; ++n) acc[m][n] = MFMA16(af[m], bf[n], acc[m][n]);
    SETPRIO0;
    WAITL_BAR;
  }
#pragma unroll
  for (int m = 0; m < 4; ++m)
#pragma unroll
    for (int r4 = 0; r4 < 4; ++r4) {
      const int row = bm * 128 + wm * 64 + m * 16 + fg * 4 + r4;
      const size_t rbase = (size_t)row * 1024 + bn * 64 + wn * 32 + fr;
#pragma unroll
      for (int n = 0; n < 2; ++n)
        out[rbase + n * 16] = acc[m][n][r4] + bo[bn * 64 + wn * 32 + n * 16 + fr];
    }
}

// ---- stats: per-(b,h,j) column max (log2 domain) + reciprocal sum of exp2 ----
__global__ __launch_bounds__(512) void stats_kernel(const bf16* __restrict__ Qh_g, const bf16* __restrict__ Ql_g,
                                                    const bf16* __restrict__ Kh_g, const bf16* __restrict__ Kl_g,
                                                    float* __restrict__ colmax, float* __restrict__ csuminv)
{
  __shared__ __align__(16) bf16 smh[2][8192], sml[2][8192];   // [buf][128*64], K staged via buf1
  const int swz = (blockIdx.x & 7) * 64 + (blockIdx.x >> 3);
  const int bh = swz >> 4, jb = swz & 15;
  const int b = bh >> 4, h = bh & 15;
  const int t = threadIdx.x, lane = t & 63, w = t >> 6;
  const int fr = lane & 15, fg = lane >> 4;
  const int lr = lane >> 3, lc = lane & 7;

  auto stageQ = [&](int buf, int it) {
#pragma unroll
    for (int q = 0; q < 2; ++q) {
      const int r = (q * 8 + w) * 8 + lr;
      const size_t g = (size_t)(b * 2048 + it * 128 + r) * 1024 + h * 64 + ((lc ^ (r & 7)) * 8);
      gload16(Qh_g + g, &smh[buf][(q * 8 + w) * 512]);
      gload16(Ql_g + g, &sml[buf][(q * 8 + w) * 512]);
    }
  };

  // stage K into buf1 (4 ops), then Q it=0 into buf0 (4 ops)
#pragma unroll
  for (int q = 0; q < 2; ++q) {
    const int r = (q * 8 + w) * 8 + lr;
    const size_t g = (size_t)(b * 2048 + jb * 128 + r) * 1024 + h * 64 + ((lc ^ (r & 7)) * 8);
    gload16(Kh_g + g, &smh[1][(q * 8 + w) * 512]);
    gload16(Kl_g + g, &sml[1][(q * 8 + w) * 512]);
  }
  stageQ(0, 0);
  WAITV_BAR(4);              // K done (Q0 still in flight)
  bf16x8 kfh[2], kfl[2];
#pragma unroll
  for (int ks = 0; ks < 2; ++ks) {
    const int rr = w * 16 + fr;
    const int cc = (ks * 32 + fg * 8) ^ ((rr & 7) << 3);
    kfh[ks] = *(bf16x8*)&smh[1][rr * 64 + cc];
    kfl[ks] = *(bf16x8*)&sml[1][rr * 64 + cc];
  }
  WAITL_BAR;                 // K frag reads done -> buf1 reusable

  float rm[4] = {-1e30f, -1e30f, -1e30f, -1e30f};
  float rs[4] = {0.f, 0.f, 0.f, 0.f};
  for (int it = 0; it < 16; ++it) {
    const int cur = it & 1;
    if (it < 15) { stageQ(cur ^ 1, it + 1); WAITV_BAR(4); }
    else         { WAITV_BAR(0); }
    f32x4 acc[8] = {};
    SETPRIO1;
#pragma unroll
    for (int ks = 0; ks < 2; ++ks)
#pragma unroll
      for (int n = 0; n < 8; ++n) {
        const int rr = n * 16 + fr;
        const int cc = (ks * 32 + fg * 8) ^ ((rr & 7) << 3);
        const bf16x8 qf = *(bf16x8*)&smh[cur][rr * 64 + cc];
        const bf16x8 lf = *(bf16x8*)&sml[cur][rr * 64 + cc];
        acc[n] = MFMA16(kfh[ks], qf, acc[n]);
        acc[n] = MFMA16(kfh[ks], lf, acc[n]);
        acc[n] = MFMA16(kfl[ks], qf, acc[n]);
      }
    SETPRIO0;
    // per-lane online update (no cross-lane ops in the loop)
#pragma unroll
    for (int r4 = 0; r4 < 4; ++r4) {
      const float m = fmaxf(fmaxf(fmaxf(acc[0][r4], acc[1][r4]), fmaxf(acc[2][r4], acc[3][r4])),
                            fmaxf(fmaxf(acc[4][r4], acc[5][r4]), fmaxf(acc[6][r4], acc[7][r4])));
      const float mn = fmaxf(rm[r4], m);
      float ts = 0.f;
#pragma unroll
      for (int n = 0; n < 8; ++n) ts += EXP2(acc[n][r4] - mn);
      rs[r4] = rs[r4] * EXP2(rm[r4] - mn) + ts;
      rm[r4] = mn;
    }
    WAITL_BAR;
  }
  // cross-lane combine: the 16 lanes varying fr share the same j
#pragma unroll
  for (int r4 = 0; r4 < 4; ++r4) {
    float M = rm[r4];
#pragma unroll
    for (int off = 1; off < 16; off <<= 1) M = fmaxf(M, __shfl_xor(M, off));
    float s = rs[r4] * EXP2(rm[r4] - M);
#pragma unroll
    for (int off = 1; off < 16; off <<= 1) s += __shfl_xor(s, off);
    rm[r4] = M;
    rs[r4] = s;
  }
  if (fr == 0) {
#pragma unroll
    for (int r4 = 0; r4 < 4; ++r4) {
      const int j = jb * 128 + w * 16 + fg * 4 + r4;
      colmax[bh * 2048 + j] = rm[r4];
      csuminv[bh * 2048 + j] = 1.0f / rs[r4];
    }
  }
}

// ---- attn: gload_lds dbuf K/V staging (r12); P stores row-outer for offset folding ----
__global__ __launch_bounds__(256) void attn_kernel(const bf16* __restrict__ Qh_g, const bf16* __restrict__ Ql_g,
                                                   const bf16* __restrict__ Kh_g, const bf16* __restrict__ Kl_g,
                                                   const bf16* __restrict__ Vt_g,
                                                   const float* __restrict__ colmax, const float* __restrict__ csuminv,
                                                   float* __restrict__ P, bf16* __restrict__ attnb)
{
  // layout: dbuf [2][3][64*64] bf16 = 48KB at 0 (Kh,Kl,Vt per buf); Pb [128][72] at 49152
  __shared__ __align__(16) unsigned char smem[67584];
  bf16(*Pb)[72] = (bf16(*)[72])(smem + 49152);
  bf16(*Qh)[72] = (bf16(*)[72])smem;                  // overlay: 128 rows (prologue only)
  bf16(*Ql)[72] = (bf16(*)[72])(smem + 18432);

  const int swz = (blockIdx.x & 7) * 64 + (blockIdx.x >> 3);
  const int bh = swz >> 4, ib = swz & 15;
  const int b = bh >> 4, h = bh & 15;
  const int t = threadIdx.x, lane = t & 63, w = t >> 6;
  const int fr = lane & 15, fg = lane >> 4;

  // prologue: stage Q i-block (padded overlay) and preload fragments
#pragma unroll
  for (int q = 0; q < 4; ++q) {
    const int u = q * 256 + t, r = u >> 3, c8 = (u & 7) * 8;
    const size_t g = (size_t)(b * 2048 + ib * 128 + r) * 1024 + h * 64 + c8;
    *(bf16x8*)&Qh[r][c8] = *(const bf16x8*)(Qh_g + g);
    *(bf16x8*)&Ql[r][c8] = *(const bf16x8*)(Ql_g + g);
  }
  WAITL_BAR;
  bf16x8 qfh[2][2], qfl[2][2];
#pragma unroll
  for (int mf = 0; mf < 2; ++mf)
#pragma unroll
    for (int ks = 0; ks < 2; ++ks) {
      qfh[mf][ks] = *(bf16x8*)&Qh[w * 32 + mf * 16 + fr][ks * 32 + fg * 8];
      qfl[mf][ks] = *(bf16x8*)&Ql[w * 32 + mf * 16 + fr][ks * 32 + fg * 8];
    }
  WAITL_BAR;       // all waves done reading Q overlay -> dbuf region free

  // K/V tile stage: direct-to-LDS, source chunks pre-swizzled (chunk ^ (row&7))
  auto stage = [&](int buf, int jt1) {
    bf16* base = (bf16*)(smem + buf * 24576);
#pragma unroll
    for (int q = 0; q < 2; ++q) {
      const int u = q * 256 + t, r = u >> 3, lc = u & 7;
      const int sc = (lc ^ (r & 7)) * 8;
      const size_t gk = (size_t)(b * 2048 + jt1 * 64 + r) * 1024 + h * 64 + sc;
      gload16(Kh_g + gk, base + u * 8);
      gload16(Kl_g + gk, base + 4096 + u * 8);
      gload16(Vt_g + (size_t)(bh * 64 + r) * 2048 + jt1 * 64 + sc, base + 8192 + u * 8);
    }
  };

  stage(0, 0);
  WAITV_BAR(0);    // tile 0 ready

  f32x4 oacc[2][4] = {};
  for (int jt = 0; jt < 32; ++jt) {
    const int cur = jt & 1;
    bf16* bufK  = (bf16*)(smem + cur * 24576);
    bf16* bufKl = bufK + 4096;
    bf16* bufV  = bufK + 8192;
    // stats loads: consumed at exp phase (compiler-managed wait, hides under S-MFMA)
    float cmr[4], rcr[4];
#pragma unroll
    for (int nj = 0; nj < 4; ++nj) {
      const int jg = jt * 64 + nj * 16 + fr;
      cmr[nj] = colmax[bh * 2048 + jg];
      rcr[nj] = csuminv[bh * 2048 + jg];
    }
    // S tile = Q . K^T (scaled by 8*log2e via K); swizzled LDS reads
    f32x4 s[2][4] = {};
    SETPRIO1;
#pragma unroll
    for (int ks = 0; ks < 2; ++ks)
#pragma unroll
      for (int nj = 0; nj < 4; ++nj) {
        const int rr = nj * 16 + fr;
        const int cc = ((ks * 4 + fg) ^ (rr & 7)) * 8;
        const bf16x8 khf = *(bf16x8*)(bufK + rr * 64 + cc);
        const bf16x8 klf = *(bf16x8*)(bufKl + rr * 64 + cc);
#pragma unroll
        for (int mf = 0; mf < 2; ++mf) {
          s[mf][nj] = MFMA16(qfh[mf][ks], khf, s[mf][nj]);
          s[mf][nj] = MFMA16(qfh[mf][ks], klf, s[mf][nj]);
          s[mf][nj] = MFMA16(qfl[mf][ks], khf, s[mf][nj]);
        }
      }
    SETPRIO0;
    // normalize in place (s := P) and stash bf16 copy in LDS
#pragma unroll
    for (int nj = 0; nj < 4; ++nj)
#pragma unroll
      for (int mf = 0; mf < 2; ++mf)
#pragma unroll
        for (int r4 = 0; r4 < 4; ++r4) {
          const int il = w * 32 + mf * 16 + fg * 4 + r4;
          const float pv = EXP2(s[mf][nj][r4] - cmr[nj]) * rcr[nj];
          s[mf][nj][r4] = pv;
          Pb[il][nj * 16 + fr] = (bf16)pv;
        }
    WAITL_BAR;     // BAR1: Pb visible; all waves past iter jt-1 entirely -> buf[cur^1] free
    if (jt < 31) stage(cur ^ 1, jt + 1);   // 6 loads, pinned before the P stores
    SCHEDBAR;
    // P global stores: row-fixed outer, nj inner -> 4 offset-folded stores per base
#pragma unroll
    for (int mf = 0; mf < 2; ++mf)
#pragma unroll
      for (int r4 = 0; r4 < 4; ++r4) {
        const int il = w * 32 + mf * 16 + fg * 4 + r4;
        float* rowp = P + (size_t)(bh * 2048 + ib * 128 + il) * 2048 + jt * 64 + fr;
#pragma unroll
        for (int nj = 0; nj < 4; ++nj) rowp[nj * 16] = s[mf][nj][r4];
      }
    SETPRIO1;
#pragma unroll
    for (int ks = 0; ks < 2; ++ks) {
      bf16x8 pa[2];
#pragma unroll
      for (int mf = 0; mf < 2; ++mf) pa[mf] = *(bf16x8*)&Pb[w * 32 + mf * 16 + fr][ks * 32 + fg * 8];
#pragma unroll
      for (int nd = 0; nd < 4; ++nd) {
        const int rr = nd * 16 + fr;
        const int cc = ((ks * 4 + fg) ^ (rr & 7)) * 8;
        const bf16x8 vbf = *(bf16x8*)(bufV + rr * 64 + cc);
#pragma unroll
        for (int mf = 0; mf < 2; ++mf) oacc[mf][nd] = MFMA16(pa[mf], vbf, oacc[mf][nd]);
      }
    }
    SETPRIO0;
    // end-bar: vmcnt(32) = keep only the 32 P stores in flight -> stage drained
    if (jt < 31) { WAITV_BAR(32); }
  }
#pragma unroll
  for (int mf = 0; mf < 2; ++mf)
#pragma unroll
    for (int nd = 0; nd < 4; ++nd)
#pragma unroll
      for (int r4 = 0; r4 < 4; ++r4) {
        const int il = ib * 128 + w * 32 + mf * 16 + fg * 4 + r4;
        attnb[(size_t)(b * 2048 + il) * 1024 + h * 64 + nd * 16 + fr] = (bf16)oacc[mf][nd][r4];
      }
}

extern "C" void kernel_launch(void* const* d_in, const int* in_sizes, int n_in,
                              void* d_out, int out_size, void* d_ws, size_t ws_size,
                              hipStream_t stream)
{
  const float* query = (const float*)d_in[0];
  const float* key   = (const float*)d_in[1];
  const float* value = (const float*)d_in[2];
  const float* Wq    = (const float*)d_in[3];
  const float* Wk    = (const float*)d_in[4];
  const float* Wv    = (const float*)d_in[5];
  const float* Wo    = (const float*)d_in[6];
  const float* bo    = (const float*)d_in[7];

  float* out = (float*)d_out;                 // 2*2048*1024 fp32
  float* P   = out + 4194304;                 // attn_weight: 2*16*2048*2048 fp32

  // --- scratch inside P (dead until attn_kernel writes it) ---
  bf16* qh  = (bf16*)(P + 0);
  bf16* ql  = (bf16*)(P + 2097152);
  bf16* kh  = (bf16*)(P + 4194304);
  bf16* kl  = (bf16*)(P + 6291456);
  bf16* wqh = (bf16*)(P + 8388608);
  bf16* wql = (bf16*)(P + 8912896);
  bf16* wkh = (bf16*)(P + 9437184);
  bf16* wkl = (bf16*)(P + 9961472);
  bf16* vb  = (bf16*)(P + 10485760);
  bf16* wvb = (bf16*)(P + 12582912);

  // --- persistent workspace ---
  float* ws   = (float*)d_ws;
  bf16* Qh_g  = (bf16*)(ws + 0);          // 4096x1024 bf16 each
  bf16* Ql_g  = (bf16*)(ws + 2097152);
  bf16* Kh_g  = (bf16*)(ws + 4194304);
  bf16* Kl_g  = (bf16*)(ws + 6291456);
  bf16* Vt_g  = (bf16*)(ws + 8388608);    // [(b*16+h)*64+d][2048]
  bf16* attnb = (bf16*)(ws + 10485760);   // 4096x1024 bf16
  bf16* wob   = (bf16*)(ws + 12582912);   // 1024x1024 bf16
  float* cmax = ws + 13107200;            // 32*2048
  float* csui = ws + 13172736;

  conv_kernel<<<16384, 256, 0, stream>>>(query, key, value, Wq, Wk, Wv, Wo,
                                         qh, ql, kh, kl, wqh, wql, wkh, wkl, vb, wvb, wob);
  proj_kernel<<<dim3(256, 3), 256, 0, stream>>>(qh, ql, kh, kl, wqh, wql, wkh, wkl, vb, wvb,
                                                Qh_g, Ql_g, Kh_g, Kl_g, Vt_g);
  stats_kernel<<<512, 512, 0, stream>>>(Qh_g, Ql_g, Kh_g, Kl_g, cmax, csui);
  attn_kernel<<<512, 256, 0, stream>>>(Qh_g, Ql_g, Kh_g, Kl_g, Vt_g, cmax, csui, P, attnb);
  out_kernel<<<512, 256, 0, stream>>>(attnb, wob, bo, out);
}